// Round 9
// baseline (125.293 us; speedup 1.0000x reference)
//
#include <hip/hip_runtime.h>

#define F_IN 128
#define CH   128

typedef __attribute__((ext_vector_type(8))) short bf16x8;
typedef __attribute__((ext_vector_type(4))) float f32x4;
typedef __attribute__((ext_vector_type(2))) float f32x2;
typedef __attribute__((ext_vector_type(4))) unsigned u32x4;

// f32 -> bf16 round-to-nearest-even
static __device__ __forceinline__ ushort f2b(float f) {
  union { float f; unsigned u; } v; v.f = f;
  const unsigned u = v.u;
  return (ushort)((u + 0x7FFFu + ((u >> 16) & 1u)) >> 16);
}

// ---------------------------------------------------------------------------
// Phase 1 (fused): blocks [0, gemm_blocks) do XW = X @ W via bf16 MFMA,
//   then quantize each output row to int8 (offset-binary, per-node scale
//   s[r] = rowmax/127) -> 12.8 MB table + 400 KB scales. 128 rows/block
//   (R8 lesson: 256-row blocks load-balance worse, no win).
// blocks [gemm_blocks, ...): row_ptr via BOUNDARY SCAN over sorted edge_row
//   (thread e writes row_ptr[(edge_row[e], edge_row[e+1]]] = e+1) — replaces
//   the 22-deep dependent-load binary search tail (R8 post-mortem).
// mfma_f32_16x16x32_bf16 layouts (guide §3, m89-verified):
//   A frag: row = lane&15, k = (lane>>4)*8 + j
//   B frag: col = lane&15, k = (lane>>4)*8 + j
//   C/D   : col = lane&15, row = (lane>>4)*4 + reg
// ---------------------------------------------------------------------------
__global__ __launch_bounds__(512) void gemm_rowptr_fused(
    const float* __restrict__ x, const float* __restrict__ w,
    unsigned char* __restrict__ xwq, float* __restrict__ scale,
    const int* __restrict__ edge_row, int* __restrict__ row_ptr,
    int n, int n_edges, int gemm_blocks) {
  __shared__ __align__(16) ushort Wt[F_IN * CH];  // W^T, swizzled, 32 KB
  const int t = threadIdx.x;

  if ((int)blockIdx.x >= gemm_blocks) {
    // ---- rowptr tail blocks: boundary scan (coalesced, no dep chains) ----
    const int e = ((int)blockIdx.x - gemm_blocks) * 512 + t;
    if (e < n_edges) {
      const int a = edge_row[e];
      const int b = (e + 1 < n_edges) ? edge_row[e + 1] : n;
      if (e == 0) {
        for (int r = 0; r <= a; ++r) row_ptr[r] = 0;
      }
      for (int r = a + 1; r <= b; ++r) row_ptr[r] = e + 1;
    }
    return;
  }

  // ---- GEMM blocks ----
  // stage W^T as bf16 with XOR swizzle: byte ^= (col&7)<<4
  for (int i = t; i < (F_IN * CH) / 4; i += 512) {
    const int k  = i >> 5;          // 0..127
    const int n4 = (i & 31) << 2;   // 0,4,...,124
    const f32x4 wv = *(const f32x4*)&w[k * CH + n4];
#pragma unroll
    for (int q = 0; q < 4; ++q) {
      const int nn = n4 + q;
      const int byte = (nn * 256 + k * 2) ^ ((nn & 7) << 4);
      *(ushort*)((char*)Wt + byte) = f2b(wv[q]);
    }
  }
  __syncthreads();

  const int wave = t >> 6, lane = t & 63;
  const int li   = lane & 15;
  const int kgrp = (lane >> 4) * 8;
  const int R0   = blockIdx.x * 128 + wave * 16;
  const int arow = R0 + li;

  // A fragments (4 K-steps), f32->bf16 in-register; x read-once -> nt loads
  bf16x8 a[4];
#pragma unroll
  for (int s = 0; s < 4; ++s) {
    if (arow < n) {
      const f32x4 p0 = __builtin_nontemporal_load(
          (const f32x4*)&x[arow * F_IN + s * 32 + kgrp]);
      const f32x4 p1 = __builtin_nontemporal_load(
          (const f32x4*)&x[arow * F_IN + s * 32 + kgrp + 4]);
#pragma unroll
      for (int j = 0; j < 4; ++j) {
        a[s][j]     = (short)f2b(p0[j]);
        a[s][j + 4] = (short)f2b(p1[j]);
      }
    } else {
#pragma unroll
      for (int j = 0; j < 8; ++j) a[s][j] = (short)0;
    }
  }

  f32x4 acc[8];
#pragma unroll
  for (int t8 = 0; t8 < 8; ++t8) acc[t8] = (f32x4){0.f, 0.f, 0.f, 0.f};

#pragma unroll
  for (int t8 = 0; t8 < 8; ++t8) {
    const int col = t8 * 16 + li;
#pragma unroll
    for (int s = 0; s < 4; ++s) {
      const int byte = (col * 256 + (s * 32 + kgrp) * 2) ^ ((col & 7) << 4);
      const bf16x8 b = *(const bf16x8*)((const char*)Wt + byte);
      acc[t8] = __builtin_amdgcn_mfma_f32_16x16x32_bf16(a[s], b, acc[t8], 0, 0, 0);
    }
  }

  // Epilogue: per-row absmax (shfl over 16 channel-lanes) -> int8 quant.
  const int r0 = R0 + (lane >> 4) * 4;
#pragma unroll
  for (int i = 0; i < 4; ++i) {
    const int rr = r0 + i;
    float m = 0.f;
#pragma unroll
    for (int t8 = 0; t8 < 8; ++t8) m = fmaxf(m, fabsf(acc[t8][i]));
    m = fmaxf(m, __shfl_xor(m, 1));
    m = fmaxf(m, __shfl_xor(m, 2));
    m = fmaxf(m, __shfl_xor(m, 4));
    m = fmaxf(m, __shfl_xor(m, 8));
    const float inv = (m > 1e-20f) ? 127.f / m : 0.f;
    if (rr < n) {
      if (li == 0) scale[rr] = m * (1.f / 127.f);
#pragma unroll
      for (int t8 = 0; t8 < 8; ++t8) {
        // |acc|*inv <= 127 by construction; +128 -> [1,255], no clamp
        const float q = rintf(acc[t8][i] * inv) + 128.f;
        xwq[rr * CH + t8 * 16 + li] = (unsigned char)q;
      }
    }
  }
}

// ---------------------------------------------------------------------------
// Phase 2: SpMM, OCTET per row: 8 lanes own one row (lane l8 owns 16
// consecutive channels l8*16..l8*16+15), 8 independent rows per wave.
// Discriminating change vs R7/R8 (quarter-wave): per-lane gather widens to
// u32x4 (16B) -> 8 edges per gather instruction instead of 4: HALF the
// gather wave-instructions and lane-addresses at IDENTICAL byte traffic.
// If spmm is issue/address-rate-bound this wins ~20%; if random-line
// service-bound it is flat (-> that's the floor).
// Per 8-edge chunk (per row):
//   * meta: lane l8 loads edge (e0+l8)'s col/val + scale gather; dummy
//     slots c=0/vp=0 (hot line, vp=0 kills the FMA)
//   * c/vp via wave-private LDS slab (2 ds_write + 2 ds_read_b128/octet)
//   * 8 u32x4 gathers batch-issued, unconditional (R4 lesson)
//   * decode: 16 ch/edge/lane, f32x2 pk_fma, unconditional
// -128 offset: scalar S octet-reduced (3 shfl). Epilogue: 4 contiguous
// dwordx4 stores per lane, no masking, no cross-lane acc reduction.
// ---------------------------------------------------------------------------
#define ACCD(word, j0, vv)                                                \
  do {                                                                    \
    f32x2 lo_, hi_;                                                       \
    lo_[0] = (float)((word) & 0xFFu);                                     \
    lo_[1] = (float)(((word) >> 8) & 0xFFu);                              \
    hi_[0] = (float)(((word) >> 16) & 0xFFu);                             \
    hi_[1] = (float)((word) >> 24);                                       \
    acc2[(j0)]     = __builtin_elementwise_fma(vv, lo_, acc2[(j0)]);      \
    acc2[(j0) + 1] = __builtin_elementwise_fma(vv, hi_, acc2[(j0) + 1]);  \
  } while (0)

#define ACC16PK(U, V)                                                     \
  do {                                                                    \
    const f32x2 vv_ = {(V), (V)};                                         \
    ACCD((U)[0], 0, vv_);                                                 \
    ACCD((U)[1], 2, vv_);                                                 \
    ACCD((U)[2], 4, vv_);                                                 \
    ACCD((U)[3], 6, vv_);                                                 \
  } while (0)

__global__ __launch_bounds__(256) void spmm_owave(
    const unsigned char* __restrict__ xwq, const float* __restrict__ scale,
    const float* __restrict__ edge_val, const int* __restrict__ edge_col,
    const int* __restrict__ row_ptr, const float* __restrict__ bias,
    float* __restrict__ out, int n) {
  __shared__ int   cbuf[256];
  __shared__ float vbuf[256];
  const int tid = threadIdx.x;
  const int row = (int)((blockIdx.x * 256 + tid) >> 3);
  if (row >= n) return;
  const int l8    = tid & 7;    // owns channels l8*16 .. l8*16+15
  const int obase = tid & ~7;   // octet's LDS base
  const u32x4* __restrict__ xw4 = (const u32x4*)xwq;  // 8 u32x4 per row

  const int start = row_ptr[row], end = row_ptr[row + 1];

  f32x2 acc2[8];
#pragma unroll
  for (int j = 0; j < 8; ++j) acc2[j] = (f32x2){0.f, 0.f};
  float S = 0.f;  // per-lane sum of vp (offset correction)

  for (int e0 = start; e0 < end; e0 += 8) {
    // meta: one edge per lane (8 consecutive edges of MY row)
    const int e = e0 + l8;
    int   c_my = 0;
    float vp_my = 0.f;
    if (e < end) {
      c_my = __builtin_nontemporal_load(edge_col + e);
      vp_my = __builtin_nontemporal_load(edge_val + e) * scale[c_my];
    }
    S += vp_my;
    cbuf[tid] = c_my;     // wave-private slab: in-wave DS ordering, no barrier
    vbuf[tid] = vp_my;

    // batch-issue all 8 gathers (cols read 4-at-a-time via ds_read_b128)
    const int4 ca = *(const int4*)&cbuf[obase];
    const int4 cb = *(const int4*)&cbuf[obase + 4];
    u32x4 u[8];
    u[0] = xw4[ca.x * 8 + l8];
    u[1] = xw4[ca.y * 8 + l8];
    u[2] = xw4[ca.z * 8 + l8];
    u[3] = xw4[ca.w * 8 + l8];
    u[4] = xw4[cb.x * 8 + l8];
    u[5] = xw4[cb.y * 8 + l8];
    u[6] = xw4[cb.z * 8 + l8];
    u[7] = xw4[cb.w * 8 + l8];

    // decode: unconditional, vp=0 kills dummy slots
    const f32x4 va = *(const f32x4*)&vbuf[obase];
    const f32x4 vb = *(const f32x4*)&vbuf[obase + 4];
    ACC16PK(u[0], va[0]);
    ACC16PK(u[1], va[1]);
    ACC16PK(u[2], va[2]);
    ACC16PK(u[3], va[3]);
    ACC16PK(u[4], vb[0]);
    ACC16PK(u[5], vb[1]);
    ACC16PK(u[6], vb[2]);
    ACC16PK(u[7], vb[3]);
  }

  // S over the octet's 8 lanes (each owned distinct edges)
  S += __shfl_xor(S, 1);
  S += __shfl_xor(S, 2);
  S += __shfl_xor(S, 4);

  // epilogue: lane-local 16 consecutive channels, bias+ReLU, direct store
  const float off = 128.f * S;
  const float* a = (const float*)acc2;
  const int cb0 = l8 * 16;
#pragma unroll
  for (int q = 0; q < 4; ++q) {
    const f32x4 bv = *(const f32x4*)&bias[cb0 + q * 4];
    f32x4 o;
    o[0] = fmaxf(a[q * 4 + 0] - off + bv[0], 0.f);
    o[1] = fmaxf(a[q * 4 + 1] - off + bv[1], 0.f);
    o[2] = fmaxf(a[q * 4 + 2] - off + bv[2], 0.f);
    o[3] = fmaxf(a[q * 4 + 3] - off + bv[3], 0.f);
    __builtin_nontemporal_store(o, (f32x4*)&out[(size_t)row * CH + cb0 + q * 4]);
  }
}

extern "C" void kernel_launch(void* const* d_in, const int* in_sizes, int n_in,
                              void* d_out, int out_size, void* d_ws, size_t ws_size,
                              hipStream_t stream) {
  const float* x        = (const float*)d_in[0];
  const float* kernel   = (const float*)d_in[1];
  const float* bias     = (const float*)d_in[2];
  const float* edge_val = (const float*)d_in[3];
  const int*   edge_row = (const int*)d_in[4];
  const int*   edge_col = (const int*)d_in[5];
  float* out = (float*)d_out;

  const int n       = in_sizes[0] / F_IN;   // 100000
  const int n_edges = in_sizes[3];          // 3200000

  // ws layout: [xwq: n*CH int8 = 12.8 MB][scale: n f32][row_ptr: (n+1) int]
  unsigned char* xwq = (unsigned char*)d_ws;
  float* scale = (float*)((char*)d_ws + (size_t)n * CH);
  int* rowptr  = (int*)((char*)d_ws + (size_t)n * CH + (size_t)n * sizeof(float));

  // Phase 1 (fused): XW = X @ W (bf16 MFMA) + int8 quant + boundary-scan rowptr
  const int GB = (n + 127) / 128;
  const int RB = (n_edges + 511) / 512;
  gemm_rowptr_fused<<<GB + RB, 512, 0, stream>>>(x, kernel, xwq, scale,
                                                 edge_row, rowptr,
                                                 n, n_edges, GB);

  // Phase 2: SpMM + bias + ReLU. 32 rows per 256-thr block (octet/row).
  const int blocks = (n * 8 + 255) / 256;
  spmm_owave<<<blocks, 256, 0, stream>>>(xwq, scale, edge_val, edge_col,
                                         rowptr, bias, out, n);
}

// Round 10
// 110.413 us; speedup vs baseline: 1.1348x; 1.1348x over previous
//
#include <hip/hip_runtime.h>

#define F_IN 128
#define CH   128

typedef __attribute__((ext_vector_type(8))) short bf16x8;
typedef __attribute__((ext_vector_type(4))) float f32x4;
typedef __attribute__((ext_vector_type(2))) float f32x2;
typedef __attribute__((ext_vector_type(2))) unsigned u32x2;

// f32 -> bf16 round-to-nearest-even
static __device__ __forceinline__ ushort f2b(float f) {
  union { float f; unsigned u; } v; v.f = f;
  const unsigned u = v.u;
  return (ushort)((u + 0x7FFFu + ((u >> 16) & 1u)) >> 16);
}

// ---------------------------------------------------------------------------
// Phase 1 (fused): blocks [0, gemm_blocks) do XW = X @ W via bf16 MFMA,
//   then quantize each output row to int8 (offset-binary, per-node scale
//   s[r] = rowmax/127) -> 12.8 MB table + 400 KB scales. 128 rows/block.
// blocks [gemm_blocks, ...): row_ptr via boundary scan over sorted edge_row
//   (coalesced, no dependent-load chains).
// mfma_f32_16x16x32_bf16 layouts (guide §3, m89-verified):
//   A frag: row = lane&15, k = (lane>>4)*8 + j
//   B frag: col = lane&15, k = (lane>>4)*8 + j
//   C/D   : col = lane&15, row = (lane>>4)*4 + reg
// ---------------------------------------------------------------------------
__global__ __launch_bounds__(512) void gemm_rowptr_fused(
    const float* __restrict__ x, const float* __restrict__ w,
    unsigned char* __restrict__ xwq, float* __restrict__ scale,
    const int* __restrict__ edge_row, int* __restrict__ row_ptr,
    int n, int n_edges, int gemm_blocks) {
  __shared__ __align__(16) ushort Wt[F_IN * CH];  // W^T, swizzled, 32 KB
  const int t = threadIdx.x;

  if ((int)blockIdx.x >= gemm_blocks) {
    // ---- rowptr tail blocks: boundary scan (coalesced, no dep chains) ----
    const int e = ((int)blockIdx.x - gemm_blocks) * 512 + t;
    if (e < n_edges) {
      const int a = edge_row[e];
      const int b = (e + 1 < n_edges) ? edge_row[e + 1] : n;
      if (e == 0) {
        for (int r = 0; r <= a; ++r) row_ptr[r] = 0;
      }
      for (int r = a + 1; r <= b; ++r) row_ptr[r] = e + 1;
    }
    return;
  }

  // ---- GEMM blocks ----
  // stage W^T as bf16 with XOR swizzle: byte ^= (col&7)<<4
  for (int i = t; i < (F_IN * CH) / 4; i += 512) {
    const int k  = i >> 5;          // 0..127
    const int n4 = (i & 31) << 2;   // 0,4,...,124
    const f32x4 wv = *(const f32x4*)&w[k * CH + n4];
#pragma unroll
    for (int q = 0; q < 4; ++q) {
      const int nn = n4 + q;
      const int byte = (nn * 256 + k * 2) ^ ((nn & 7) << 4);
      *(ushort*)((char*)Wt + byte) = f2b(wv[q]);
    }
  }
  __syncthreads();

  const int wave = t >> 6, lane = t & 63;
  const int li   = lane & 15;
  const int kgrp = (lane >> 4) * 8;
  const int R0   = blockIdx.x * 128 + wave * 16;
  const int arow = R0 + li;

  // A fragments (4 K-steps), f32->bf16 in-register; x read-once -> nt loads
  bf16x8 a[4];
#pragma unroll
  for (int s = 0; s < 4; ++s) {
    if (arow < n) {
      const f32x4 p0 = __builtin_nontemporal_load(
          (const f32x4*)&x[arow * F_IN + s * 32 + kgrp]);
      const f32x4 p1 = __builtin_nontemporal_load(
          (const f32x4*)&x[arow * F_IN + s * 32 + kgrp + 4]);
#pragma unroll
      for (int j = 0; j < 4; ++j) {
        a[s][j]     = (short)f2b(p0[j]);
        a[s][j + 4] = (short)f2b(p1[j]);
      }
    } else {
#pragma unroll
      for (int j = 0; j < 8; ++j) a[s][j] = (short)0;
    }
  }

  f32x4 acc[8];
#pragma unroll
  for (int t8 = 0; t8 < 8; ++t8) acc[t8] = (f32x4){0.f, 0.f, 0.f, 0.f};

#pragma unroll
  for (int t8 = 0; t8 < 8; ++t8) {
    const int col = t8 * 16 + li;
#pragma unroll
    for (int s = 0; s < 4; ++s) {
      const int byte = (col * 256 + (s * 32 + kgrp) * 2) ^ ((col & 7) << 4);
      const bf16x8 b = *(const bf16x8*)((const char*)Wt + byte);
      acc[t8] = __builtin_amdgcn_mfma_f32_16x16x32_bf16(a[s], b, acc[t8], 0, 0, 0);
    }
  }

  // Epilogue: per-row absmax (shfl over 16 channel-lanes) -> int8 quant.
  const int r0 = R0 + (lane >> 4) * 4;
#pragma unroll
  for (int i = 0; i < 4; ++i) {
    const int rr = r0 + i;
    float m = 0.f;
#pragma unroll
    for (int t8 = 0; t8 < 8; ++t8) m = fmaxf(m, fabsf(acc[t8][i]));
    m = fmaxf(m, __shfl_xor(m, 1));
    m = fmaxf(m, __shfl_xor(m, 2));
    m = fmaxf(m, __shfl_xor(m, 4));
    m = fmaxf(m, __shfl_xor(m, 8));
    const float inv = (m > 1e-20f) ? 127.f / m : 0.f;
    if (rr < n) {
      if (li == 0) scale[rr] = m * (1.f / 127.f);
#pragma unroll
      for (int t8 = 0; t8 < 8; ++t8) {
        // |acc|*inv <= 127 by construction; +128 -> [1,255], no clamp
        const float q = rintf(acc[t8][i] * inv) + 128.f;
        xwq[rr * CH + t8 * 16 + li] = (unsigned char)q;
      }
    }
  }
}

// ---------------------------------------------------------------------------
// Phase 2: SpMM, QUARTER-WAVE per row (R7 structure — R9's octet falsified
// the gather-issue-rate hypothesis and regressed meta/store patterns), now
// with a 32-EDGE SUPERBLOCK: most rows (mean degree 32) traverse the serial
// chain meta->gather->decode ONCE instead of 2-3x (R7 post-mortem: wall =
// VALU + ~46us of per-row chain latency at ~5 waves/SIMD interleave).
// Per 32-edge superblock:
//   * meta: 2 edges per lane (e0+li, e0+16+li), issued back-to-back; dummy
//     slots c=0/vp=0 (hot line; vp=0 kills the FMA)
//   * c/vp via wave-private LDS slab (4 ds_write + 8 ds_read_b128/quarter)
//   * 32 u32x2 gathers batch-issued unconditionally (R4 lesson: keep the
//     gather batch branch-free; 64 VGPR payload)
//   * decode: f32x2 pk_fma, early-exit at 8-edge granularity (R5 split)
// -128 offset: scalar S quarter-reduced (4 shfl). Epilogue: lane li owns
// channels li*8..li*8+7 — no cross-lane acc reduction, 2 dwordx4 stores.
// ---------------------------------------------------------------------------
#define ACCD(word, j0, vv)                                                \
  do {                                                                    \
    f32x2 lo_, hi_;                                                       \
    lo_[0] = (float)((word) & 0xFFu);                                     \
    lo_[1] = (float)(((word) >> 8) & 0xFFu);                              \
    hi_[0] = (float)(((word) >> 16) & 0xFFu);                             \
    hi_[1] = (float)((word) >> 24);                                       \
    acc2[(j0)]     = __builtin_elementwise_fma(vv, lo_, acc2[(j0)]);      \
    acc2[(j0) + 1] = __builtin_elementwise_fma(vv, hi_, acc2[(j0) + 1]);  \
  } while (0)

#define ACC8PK(U, V)                                                      \
  do {                                                                    \
    const f32x2 vv_ = {(V), (V)};                                         \
    ACCD((U)[0], 0, vv_);                                                 \
    ACCD((U)[1], 2, vv_);                                                 \
  } while (0)

__global__ __launch_bounds__(256) void spmm_qwave(
    const unsigned char* __restrict__ xwq, const float* __restrict__ scale,
    const float* __restrict__ edge_val, const int* __restrict__ edge_col,
    const int* __restrict__ row_ptr, const float* __restrict__ bias,
    float* __restrict__ out, int n) {
  __shared__ int   cbuf[512];
  __shared__ float vbuf[512];
  const int tid = threadIdx.x;
  const int row = (int)((blockIdx.x * 256 + tid) >> 4);
  if (row >= n) return;
  const int li = tid & 15;          // lane-in-quarter: owns ch li*8..li*8+7
  const int qb = (tid & ~15) * 2;   // quarter's LDS base (32 entries)
  const u32x2* __restrict__ xw2 = (const u32x2*)xwq;  // 16 u32x2 per row

  const int start = row_ptr[row], end = row_ptr[row + 1];

  f32x2 acc2[4];
#pragma unroll
  for (int j = 0; j < 4; ++j) acc2[j] = (f32x2){0.f, 0.f};
  float S = 0.f;  // per-lane sum of vp (offset correction)

  for (int e0 = start; e0 < end; e0 += 32) {
    // meta: 2 edges per lane, independent back-to-back chains
    const int ea = e0 + li, eb = e0 + 16 + li;
    int   c0 = 0, c1 = 0;
    float v0 = 0.f, v1 = 0.f;
    if (ea < end) {
      c0 = __builtin_nontemporal_load(edge_col + ea);
      v0 = __builtin_nontemporal_load(edge_val + ea) * scale[c0];
    }
    if (eb < end) {
      c1 = __builtin_nontemporal_load(edge_col + eb);
      v1 = __builtin_nontemporal_load(edge_val + eb) * scale[c1];
    }
    S += v0 + v1;
    cbuf[qb + li] = c0;  cbuf[qb + 16 + li] = c1;   // wave-private slab:
    vbuf[qb + li] = v0;  vbuf[qb + 16 + li] = v1;   // in-wave DS ordering

    // batch-issue all 32 gathers (cols read 4-at-a-time via ds_read_b128)
    u32x2 u[32];
#pragma unroll
    for (int it4 = 0; it4 < 8; ++it4) {
      const int4 c4 = *(const int4*)&cbuf[qb + it4 * 4];
      u[it4 * 4 + 0] = xw2[c4.x * 16 + li];
      u[it4 * 4 + 1] = xw2[c4.y * 16 + li];
      u[it4 * 4 + 2] = xw2[c4.z * 16 + li];
      u[it4 * 4 + 3] = xw2[c4.w * 16 + li];
    }

    // decode: early-exit at 8-edge granularity (wave-uniform break)
#pragma unroll
    for (int g = 0; g < 4; ++g) {
      if (e0 + g * 8 >= end) break;
      const f32x4 va = *(const f32x4*)&vbuf[qb + g * 8];
      const f32x4 vb = *(const f32x4*)&vbuf[qb + g * 8 + 4];
      ACC8PK(u[g * 8 + 0], va[0]);
      ACC8PK(u[g * 8 + 1], va[1]);
      ACC8PK(u[g * 8 + 2], va[2]);
      ACC8PK(u[g * 8 + 3], va[3]);
      ACC8PK(u[g * 8 + 4], vb[0]);
      ACC8PK(u[g * 8 + 5], vb[1]);
      ACC8PK(u[g * 8 + 6], vb[2]);
      ACC8PK(u[g * 8 + 7], vb[3]);
    }
  }

  // S over the quarter's 16 lanes (each owned distinct edges)
  S += __shfl_xor(S, 1);
  S += __shfl_xor(S, 2);
  S += __shfl_xor(S, 4);
  S += __shfl_xor(S, 8);

  // epilogue: lane-local 8 channels, bias+ReLU, direct store — no masking
  const float off = 128.f * S;
  const float* a = (const float*)acc2;
  const int cb = li * 8;
  const f32x4 b0 = *(const f32x4*)&bias[cb];
  const f32x4 b1 = *(const f32x4*)&bias[cb + 4];
  f32x4 o0, o1;
  o0[0] = fmaxf(a[0] - off + b0[0], 0.f);
  o0[1] = fmaxf(a[1] - off + b0[1], 0.f);
  o0[2] = fmaxf(a[2] - off + b0[2], 0.f);
  o0[3] = fmaxf(a[3] - off + b0[3], 0.f);
  o1[0] = fmaxf(a[4] - off + b1[0], 0.f);
  o1[1] = fmaxf(a[5] - off + b1[1], 0.f);
  o1[2] = fmaxf(a[6] - off + b1[2], 0.f);
  o1[3] = fmaxf(a[7] - off + b1[3], 0.f);
  __builtin_nontemporal_store(o0, (f32x4*)&out[(size_t)row * CH + cb]);
  __builtin_nontemporal_store(o1, (f32x4*)&out[(size_t)row * CH + cb + 4]);
}

extern "C" void kernel_launch(void* const* d_in, const int* in_sizes, int n_in,
                              void* d_out, int out_size, void* d_ws, size_t ws_size,
                              hipStream_t stream) {
  const float* x        = (const float*)d_in[0];
  const float* kernel   = (const float*)d_in[1];
  const float* bias     = (const float*)d_in[2];
  const float* edge_val = (const float*)d_in[3];
  const int*   edge_row = (const int*)d_in[4];
  const int*   edge_col = (const int*)d_in[5];
  float* out = (float*)d_out;

  const int n       = in_sizes[0] / F_IN;   // 100000
  const int n_edges = in_sizes[3];          // 3200000

  // ws layout: [xwq: n*CH int8 = 12.8 MB][scale: n f32][row_ptr: (n+1) int]
  unsigned char* xwq = (unsigned char*)d_ws;
  float* scale = (float*)((char*)d_ws + (size_t)n * CH);
  int* rowptr  = (int*)((char*)d_ws + (size_t)n * CH + (size_t)n * sizeof(float));

  // Phase 1 (fused): XW = X @ W (bf16 MFMA) + int8 quant + boundary-scan rowptr
  const int GB = (n + 127) / 128;
  const int RB = (n_edges + 511) / 512;
  gemm_rowptr_fused<<<GB + RB, 512, 0, stream>>>(x, kernel, xwq, scale,
                                                 edge_row, rowptr,
                                                 n, n_edges, GB);

  // Phase 2: SpMM + bias + ReLU. 16 rows per 256-thr block (quarter-wave/row).
  const int blocks = (n * 16 + 255) / 256;
  spmm_qwave<<<blocks, 256, 0, stream>>>(xwq, scale, edge_val, edge_col,
                                         rowptr, bias, out, n);
}

// Round 11
// 108.094 us; speedup vs baseline: 1.1591x; 1.0215x over previous
//
#include <hip/hip_runtime.h>

#define F_IN 128
#define CH   128

typedef __attribute__((ext_vector_type(8))) short bf16x8;
typedef __attribute__((ext_vector_type(4))) float f32x4;
typedef __attribute__((ext_vector_type(2))) float f32x2;
typedef __attribute__((ext_vector_type(2))) unsigned u32x2;

// f32 -> bf16 round-to-nearest-even
static __device__ __forceinline__ ushort f2b(float f) {
  union { float f; unsigned u; } v; v.f = f;
  const unsigned u = v.u;
  return (ushort)((u + 0x7FFFu + ((u >> 16) & 1u)) >> 16);
}

// ---------------------------------------------------------------------------
// Phase 1 (fused): blocks [0, gemm_blocks) do XW = X @ W via bf16 MFMA,
//   then quantize each output row to int8 (offset-binary, per-node scale
//   s[r] = rowmax/127) -> 12.8 MB table + 400 KB scales. 128 rows/block.
//   NEW (R11): quant epilogue goes through a wave-private LDS slab (Wt
//   reused after barrier) -> coalesced u32x2 global stores (was 32 global
//   byte-stores per lane = 16B/wave-instr effective width).
// blocks [gemm_blocks, ...): row_ptr boundary scan, 4 edges/thread (int4).
// mfma_f32_16x16x32_bf16 layouts (guide §3, m89-verified):
//   A frag: row = lane&15, k = (lane>>4)*8 + j
//   B frag: col = lane&15, k = (lane>>4)*8 + j
//   C/D   : col = lane&15, row = (lane>>4)*4 + reg
// ---------------------------------------------------------------------------
__global__ __launch_bounds__(512) void gemm_rowptr_fused(
    const float* __restrict__ x, const float* __restrict__ w,
    unsigned char* __restrict__ xwq, float* __restrict__ scale,
    const int* __restrict__ edge_row, int* __restrict__ row_ptr,
    int n, int n_edges, int gemm_blocks) {
  __shared__ __align__(16) ushort Wt[F_IN * CH];  // W^T, swizzled, 32 KB
  const int t = threadIdx.x;

  if ((int)blockIdx.x >= gemm_blocks) {
    // ---- rowptr tail blocks: boundary scan, 4 edges per thread ----
    const int base = (((int)blockIdx.x - gemm_blocks) * 512 + t) * 4;
    if (base < n_edges) {
      const int4 er = *(const int4*)&edge_row[base];
      const int nxt = (base + 4 < n_edges) ? edge_row[base + 4] : n;
      if (base == 0) {
        for (int r = 0; r <= er.x; ++r) row_ptr[r] = 0;
      }
      for (int r = er.x + 1; r <= er.y; ++r) row_ptr[r] = base + 1;
      for (int r = er.y + 1; r <= er.z; ++r) row_ptr[r] = base + 2;
      for (int r = er.z + 1; r <= er.w; ++r) row_ptr[r] = base + 3;
      for (int r = er.w + 1; r <= nxt;  ++r) row_ptr[r] = base + 4;
    }
    return;
  }

  // ---- GEMM blocks ----
  // stage W^T as bf16 with XOR swizzle: byte ^= (col&7)<<4
  for (int i = t; i < (F_IN * CH) / 4; i += 512) {
    const int k  = i >> 5;          // 0..127
    const int n4 = (i & 31) << 2;   // 0,4,...,124
    const f32x4 wv = *(const f32x4*)&w[k * CH + n4];
#pragma unroll
    for (int q = 0; q < 4; ++q) {
      const int nn = n4 + q;
      const int byte = (nn * 256 + k * 2) ^ ((nn & 7) << 4);
      *(ushort*)((char*)Wt + byte) = f2b(wv[q]);
    }
  }
  __syncthreads();

  const int wave = t >> 6, lane = t & 63;
  const int li   = lane & 15;
  const int kgrp = (lane >> 4) * 8;
  const int R0   = blockIdx.x * 128 + wave * 16;
  const int arow = R0 + li;

  // A fragments (4 K-steps), f32->bf16 in-register; x read-once -> nt loads
  bf16x8 a[4];
#pragma unroll
  for (int s = 0; s < 4; ++s) {
    if (arow < n) {
      const f32x4 p0 = __builtin_nontemporal_load(
          (const f32x4*)&x[arow * F_IN + s * 32 + kgrp]);
      const f32x4 p1 = __builtin_nontemporal_load(
          (const f32x4*)&x[arow * F_IN + s * 32 + kgrp + 4]);
#pragma unroll
      for (int j = 0; j < 4; ++j) {
        a[s][j]     = (short)f2b(p0[j]);
        a[s][j + 4] = (short)f2b(p1[j]);
      }
    } else {
#pragma unroll
      for (int j = 0; j < 8; ++j) a[s][j] = (short)0;
    }
  }

  f32x4 acc[8];
#pragma unroll
  for (int t8 = 0; t8 < 8; ++t8) acc[t8] = (f32x4){0.f, 0.f, 0.f, 0.f};

#pragma unroll
  for (int t8 = 0; t8 < 8; ++t8) {
    const int col = t8 * 16 + li;
#pragma unroll
    for (int s = 0; s < 4; ++s) {
      const int byte = (col * 256 + (s * 32 + kgrp) * 2) ^ ((col & 7) << 4);
      const bf16x8 b = *(const bf16x8*)((const char*)Wt + byte);
      acc[t8] = __builtin_amdgcn_mfma_f32_16x16x32_bf16(a[s], b, acc[t8], 0, 0, 0);
    }
  }

  // Epilogue A: per-row absmax (shfl over 16 channel-lanes) + scale store
  float inv4[4];
  const int r0 = R0 + (lane >> 4) * 4;
#pragma unroll
  for (int i = 0; i < 4; ++i) {
    float m = 0.f;
#pragma unroll
    for (int t8 = 0; t8 < 8; ++t8) m = fmaxf(m, fabsf(acc[t8][i]));
    m = fmaxf(m, __shfl_xor(m, 1));
    m = fmaxf(m, __shfl_xor(m, 2));
    m = fmaxf(m, __shfl_xor(m, 4));
    m = fmaxf(m, __shfl_xor(m, 8));
    inv4[i] = (m > 1e-20f) ? 127.f / m : 0.f;
    const int rr = r0 + i;
    if (rr < n && li == 0) scale[rr] = m * (1.f / 127.f);
  }

  // Epilogue B: quantize through wave-private LDS slab -> coalesced stores.
  __syncthreads();  // all waves done reading Wt; safe to reuse as byte buffer
  unsigned char* qb8 = (unsigned char*)Wt + wave * 2048;  // 16 rows x 128 B
#pragma unroll
  for (int i = 0; i < 4; ++i) {
    const int rl = (lane >> 4) * 4 + i;   // row-local 0..15
#pragma unroll
    for (int t8 = 0; t8 < 8; ++t8) {
      // |acc|*inv <= 127 by construction; +128 -> [1,255], no clamp
      const float q = rintf(acc[t8][i] * inv4[i]) + 128.f;
      qb8[rl * 128 + t8 * 16 + li] = (unsigned char)q;
    }
  }
  // wave-private region: compiler orders ds reads after writes via lgkmcnt
#pragma unroll
  for (int p = 0; p < 4; ++p) {
    const int idx = p * 64 + lane;        // 0..255
    const int rl  = idx >> 4;             // row-local 0..15
    const int off = (idx & 15) * 8;       // byte offset in row
    const int rr  = R0 - (lane >> 4) * 16 + rl;  // wave base + rl
    // R0 = block*128 + wave*16 (lane-invariant part); recompute cleanly:
    const int rrow = blockIdx.x * 128 + wave * 16 + rl;
    (void)rr;
    if (rrow < n) {
      const u32x2 v = *(const u32x2*)&qb8[rl * 128 + off];
      *(u32x2*)&xwq[(size_t)rrow * CH + off] = v;
    }
  }
}

// ---------------------------------------------------------------------------
// Phase 2: SpMM, QUARTER-WAVE per row, 32-edge superblock (R10 structure,
// frozen), now 512-thread blocks (32 rows/block): denser per-CU wave packing
// to lift occupancy (R10: 53%, wall = VALU + ~46us exposed latency at only
// ~4 waves/SIMD interleave).
// Per 32-edge superblock:
//   * meta: 2 edges per lane (e0+li, e0+16+li); dummy slots c=0/vp=0
//   * c/vp via wave-private LDS slab (ds ordering, no barrier)
//   * 32 u32x2 gathers batch-issued unconditionally
//   * decode: f32x2 pk_fma, early-exit at 8-edge granularity
// -128 offset: scalar S quarter-reduced (4 shfl). Epilogue: lane li owns
// channels li*8..li*8+7 — no cross-lane acc reduction, 2 dwordx4 stores.
// ---------------------------------------------------------------------------
#define ACCD(word, j0, vv)                                                \
  do {                                                                    \
    f32x2 lo_, hi_;                                                       \
    lo_[0] = (float)((word) & 0xFFu);                                     \
    lo_[1] = (float)(((word) >> 8) & 0xFFu);                              \
    hi_[0] = (float)(((word) >> 16) & 0xFFu);                             \
    hi_[1] = (float)((word) >> 24);                                       \
    acc2[(j0)]     = __builtin_elementwise_fma(vv, lo_, acc2[(j0)]);      \
    acc2[(j0) + 1] = __builtin_elementwise_fma(vv, hi_, acc2[(j0) + 1]);  \
  } while (0)

#define ACC8PK(U, V)                                                      \
  do {                                                                    \
    const f32x2 vv_ = {(V), (V)};                                         \
    ACCD((U)[0], 0, vv_);                                                 \
    ACCD((U)[1], 2, vv_);                                                 \
  } while (0)

__global__ __launch_bounds__(512) void spmm_qwave(
    const unsigned char* __restrict__ xwq, const float* __restrict__ scale,
    const float* __restrict__ edge_val, const int* __restrict__ edge_col,
    const int* __restrict__ row_ptr, const float* __restrict__ bias,
    float* __restrict__ out, int n) {
  __shared__ int   cbuf[1024];
  __shared__ float vbuf[1024];
  const int tid = threadIdx.x;
  const int row = (int)((blockIdx.x * 512 + tid) >> 4);
  if (row >= n) return;
  const int li = tid & 15;          // lane-in-quarter: owns ch li*8..li*8+7
  const int qb = (tid & ~15) * 2;   // quarter's LDS base (32 entries)
  const u32x2* __restrict__ xw2 = (const u32x2*)xwq;  // 16 u32x2 per row

  const int start = row_ptr[row], end = row_ptr[row + 1];

  f32x2 acc2[4];
#pragma unroll
  for (int j = 0; j < 4; ++j) acc2[j] = (f32x2){0.f, 0.f};
  float S = 0.f;  // per-lane sum of vp (offset correction)

  for (int e0 = start; e0 < end; e0 += 32) {
    // meta: 2 edges per lane, independent back-to-back chains
    const int ea = e0 + li, eb = e0 + 16 + li;
    int   c0 = 0, c1 = 0;
    float v0 = 0.f, v1 = 0.f;
    if (ea < end) {
      c0 = __builtin_nontemporal_load(edge_col + ea);
      v0 = __builtin_nontemporal_load(edge_val + ea) * scale[c0];
    }
    if (eb < end) {
      c1 = __builtin_nontemporal_load(edge_col + eb);
      v1 = __builtin_nontemporal_load(edge_val + eb) * scale[c1];
    }
    S += v0 + v1;
    cbuf[qb + li] = c0;  cbuf[qb + 16 + li] = c1;   // wave-private slab:
    vbuf[qb + li] = v0;  vbuf[qb + 16 + li] = v1;   // in-wave DS ordering

    // batch-issue all 32 gathers (cols read 4-at-a-time via ds_read_b128)
    u32x2 u[32];
#pragma unroll
    for (int it4 = 0; it4 < 8; ++it4) {
      const int4 c4 = *(const int4*)&cbuf[qb + it4 * 4];
      u[it4 * 4 + 0] = xw2[c4.x * 16 + li];
      u[it4 * 4 + 1] = xw2[c4.y * 16 + li];
      u[it4 * 4 + 2] = xw2[c4.z * 16 + li];
      u[it4 * 4 + 3] = xw2[c4.w * 16 + li];
    }

    // decode: early-exit at 8-edge granularity (wave-uniform break)
#pragma unroll
    for (int g = 0; g < 4; ++g) {
      if (e0 + g * 8 >= end) break;
      const f32x4 va = *(const f32x4*)&vbuf[qb + g * 8];
      const f32x4 vb = *(const f32x4*)&vbuf[qb + g * 8 + 4];
      ACC8PK(u[g * 8 + 0], va[0]);
      ACC8PK(u[g * 8 + 1], va[1]);
      ACC8PK(u[g * 8 + 2], va[2]);
      ACC8PK(u[g * 8 + 3], va[3]);
      ACC8PK(u[g * 8 + 4], vb[0]);
      ACC8PK(u[g * 8 + 5], vb[1]);
      ACC8PK(u[g * 8 + 6], vb[2]);
      ACC8PK(u[g * 8 + 7], vb[3]);
    }
  }

  // S over the quarter's 16 lanes (each owned distinct edges)
  S += __shfl_xor(S, 1);
  S += __shfl_xor(S, 2);
  S += __shfl_xor(S, 4);
  S += __shfl_xor(S, 8);

  // epilogue: lane-local 8 channels, bias+ReLU, direct store — no masking
  const float off = 128.f * S;
  const float* a = (const float*)acc2;
  const int cb = li * 8;
  const f32x4 b0 = *(const f32x4*)&bias[cb];
  const f32x4 b1 = *(const f32x4*)&bias[cb + 4];
  f32x4 o0, o1;
  o0[0] = fmaxf(a[0] - off + b0[0], 0.f);
  o0[1] = fmaxf(a[1] - off + b0[1], 0.f);
  o0[2] = fmaxf(a[2] - off + b0[2], 0.f);
  o0[3] = fmaxf(a[3] - off + b0[3], 0.f);
  o1[0] = fmaxf(a[4] - off + b1[0], 0.f);
  o1[1] = fmaxf(a[5] - off + b1[1], 0.f);
  o1[2] = fmaxf(a[6] - off + b1[2], 0.f);
  o1[3] = fmaxf(a[7] - off + b1[3], 0.f);
  __builtin_nontemporal_store(o0, (f32x4*)&out[(size_t)row * CH + cb]);
  __builtin_nontemporal_store(o1, (f32x4*)&out[(size_t)row * CH + cb + 4]);
}

extern "C" void kernel_launch(void* const* d_in, const int* in_sizes, int n_in,
                              void* d_out, int out_size, void* d_ws, size_t ws_size,
                              hipStream_t stream) {
  const float* x        = (const float*)d_in[0];
  const float* kernel   = (const float*)d_in[1];
  const float* bias     = (const float*)d_in[2];
  const float* edge_val = (const float*)d_in[3];
  const int*   edge_row = (const int*)d_in[4];
  const int*   edge_col = (const int*)d_in[5];
  float* out = (float*)d_out;

  const int n       = in_sizes[0] / F_IN;   // 100000
  const int n_edges = in_sizes[3];          // 3200000

  // ws layout: [xwq: n*CH int8 = 12.8 MB][scale: n f32][row_ptr: (n+1) int]
  unsigned char* xwq = (unsigned char*)d_ws;
  float* scale = (float*)((char*)d_ws + (size_t)n * CH);
  int* rowptr  = (int*)((char*)d_ws + (size_t)n * CH + (size_t)n * sizeof(float));

  // Phase 1 (fused): XW = X @ W (bf16 MFMA) + int8 quant + boundary-scan rowptr
  const int GB = (n + 127) / 128;
  const int RB = (n_edges / 4 + 511) / 512;
  gemm_rowptr_fused<<<GB + RB, 512, 0, stream>>>(x, kernel, xwq, scale,
                                                 edge_row, rowptr,
                                                 n, n_edges, GB);

  // Phase 2: SpMM + bias + ReLU. 32 rows per 512-thr block (quarter-wave/row).
  const int blocks = (n * 16 + 511) / 512;
  spmm_qwave<<<blocks, 512, 0, stream>>>(xwq, scale, edge_val, edge_col,
                                         rowptr, bias, out, n);
}

// Round 12
// 107.286 us; speedup vs baseline: 1.1678x; 1.0075x over previous
//
#include <hip/hip_runtime.h>

#define F_IN 128
#define CH   128

typedef __attribute__((ext_vector_type(8))) short bf16x8;
typedef __attribute__((ext_vector_type(4))) float f32x4;
typedef __attribute__((ext_vector_type(2))) float f32x2;
typedef __attribute__((ext_vector_type(2))) unsigned u32x2;

// f32 -> bf16 round-to-nearest-even
static __device__ __forceinline__ ushort f2b(float f) {
  union { float f; unsigned u; } v; v.f = f;
  const unsigned u = v.u;
  return (ushort)((u + 0x7FFFu + ((u >> 16) & 1u)) >> 16);
}

// ---------------------------------------------------------------------------
// Phase 1 (fused): blocks [0, gemm_blocks) do XW = X @ W via bf16 MFMA,
//   then quantize each output row to int8 (offset-binary, per-node scale
//   s[r] = rowmax/127) -> 12.8 MB table + 400 KB scales. 128 rows/block.
//   Quant epilogue via wave-private LDS slab -> coalesced u32x2 stores (R11).
// blocks [gemm_blocks, ...): row_ptr boundary scan, 4 edges/thread (int4).
// mfma_f32_16x16x32_bf16 layouts (guide §3, m89-verified):
//   A frag: row = lane&15, k = (lane>>4)*8 + j
//   B frag: col = lane&15, k = (lane>>4)*8 + j
//   C/D   : col = lane&15, row = (lane>>4)*4 + reg
// ---------------------------------------------------------------------------
__global__ __launch_bounds__(512) void gemm_rowptr_fused(
    const float* __restrict__ x, const float* __restrict__ w,
    unsigned char* __restrict__ xwq, float* __restrict__ scale,
    const int* __restrict__ edge_row, int* __restrict__ row_ptr,
    int n, int n_edges, int gemm_blocks) {
  __shared__ __align__(16) ushort Wt[F_IN * CH];  // W^T, swizzled, 32 KB
  const int t = threadIdx.x;

  if ((int)blockIdx.x >= gemm_blocks) {
    // ---- rowptr tail blocks: boundary scan, 4 edges per thread ----
    const int base = (((int)blockIdx.x - gemm_blocks) * 512 + t) * 4;
    if (base < n_edges) {
      const int4 er = *(const int4*)&edge_row[base];
      const int nxt = (base + 4 < n_edges) ? edge_row[base + 4] : n;
      if (base == 0) {
        for (int r = 0; r <= er.x; ++r) row_ptr[r] = 0;
      }
      for (int r = er.x + 1; r <= er.y; ++r) row_ptr[r] = base + 1;
      for (int r = er.y + 1; r <= er.z; ++r) row_ptr[r] = base + 2;
      for (int r = er.z + 1; r <= er.w; ++r) row_ptr[r] = base + 3;
      for (int r = er.w + 1; r <= nxt;  ++r) row_ptr[r] = base + 4;
    }
    return;
  }

  // ---- GEMM blocks ----
  // stage W^T as bf16 with XOR swizzle: byte ^= (col&7)<<4
  for (int i = t; i < (F_IN * CH) / 4; i += 512) {
    const int k  = i >> 5;          // 0..127
    const int n4 = (i & 31) << 2;   // 0,4,...,124
    const f32x4 wv = *(const f32x4*)&w[k * CH + n4];
#pragma unroll
    for (int q = 0; q < 4; ++q) {
      const int nn = n4 + q;
      const int byte = (nn * 256 + k * 2) ^ ((nn & 7) << 4);
      *(ushort*)((char*)Wt + byte) = f2b(wv[q]);
    }
  }
  __syncthreads();

  const int wave = t >> 6, lane = t & 63;
  const int li   = lane & 15;
  const int kgrp = (lane >> 4) * 8;
  const int R0   = blockIdx.x * 128 + wave * 16;
  const int arow = R0 + li;

  // A fragments (4 K-steps), f32->bf16 in-register; x read-once -> nt loads
  bf16x8 a[4];
#pragma unroll
  for (int s = 0; s < 4; ++s) {
    if (arow < n) {
      const f32x4 p0 = __builtin_nontemporal_load(
          (const f32x4*)&x[arow * F_IN + s * 32 + kgrp]);
      const f32x4 p1 = __builtin_nontemporal_load(
          (const f32x4*)&x[arow * F_IN + s * 32 + kgrp + 4]);
#pragma unroll
      for (int j = 0; j < 4; ++j) {
        a[s][j]     = (short)f2b(p0[j]);
        a[s][j + 4] = (short)f2b(p1[j]);
      }
    } else {
#pragma unroll
      for (int j = 0; j < 8; ++j) a[s][j] = (short)0;
    }
  }

  f32x4 acc[8];
#pragma unroll
  for (int t8 = 0; t8 < 8; ++t8) acc[t8] = (f32x4){0.f, 0.f, 0.f, 0.f};

#pragma unroll
  for (int t8 = 0; t8 < 8; ++t8) {
    const int col = t8 * 16 + li;
#pragma unroll
    for (int s = 0; s < 4; ++s) {
      const int byte = (col * 256 + (s * 32 + kgrp) * 2) ^ ((col & 7) << 4);
      const bf16x8 b = *(const bf16x8*)((const char*)Wt + byte);
      acc[t8] = __builtin_amdgcn_mfma_f32_16x16x32_bf16(a[s], b, acc[t8], 0, 0, 0);
    }
  }

  // Epilogue A: per-row absmax (shfl over 16 channel-lanes) + scale store
  float inv4[4];
  const int r0 = R0 + (lane >> 4) * 4;
#pragma unroll
  for (int i = 0; i < 4; ++i) {
    float m = 0.f;
#pragma unroll
    for (int t8 = 0; t8 < 8; ++t8) m = fmaxf(m, fabsf(acc[t8][i]));
    m = fmaxf(m, __shfl_xor(m, 1));
    m = fmaxf(m, __shfl_xor(m, 2));
    m = fmaxf(m, __shfl_xor(m, 4));
    m = fmaxf(m, __shfl_xor(m, 8));
    inv4[i] = (m > 1e-20f) ? 127.f / m : 0.f;
    const int rr = r0 + i;
    if (rr < n && li == 0) scale[rr] = m * (1.f / 127.f);
  }

  // Epilogue B: quantize through wave-private LDS slab -> coalesced stores.
  __syncthreads();  // all waves done reading Wt; safe to reuse as byte buffer
  unsigned char* qb8 = (unsigned char*)Wt + wave * 2048;  // 16 rows x 128 B
#pragma unroll
  for (int i = 0; i < 4; ++i) {
    const int rl = (lane >> 4) * 4 + i;   // row-local 0..15
#pragma unroll
    for (int t8 = 0; t8 < 8; ++t8) {
      // |acc|*inv <= 127 by construction; +128 -> [1,255], no clamp
      const float q = rintf(acc[t8][i] * inv4[i]) + 128.f;
      qb8[rl * 128 + t8 * 16 + li] = (unsigned char)q;
    }
  }
  // wave-private region: compiler orders ds reads after writes via lgkmcnt
#pragma unroll
  for (int p = 0; p < 4; ++p) {
    const int idx = p * 64 + lane;        // 0..255
    const int rl  = idx >> 4;             // row-local 0..15
    const int off = (idx & 15) * 8;       // byte offset in row
    const int rrow = blockIdx.x * 128 + wave * 16 + rl;
    if (rrow < n) {
      const u32x2 v = *(const u32x2*)&qb8[rl * 128 + off];
      *(u32x2*)&xwq[(size_t)rrow * CH + off] = v;
    }
  }
}

// ---------------------------------------------------------------------------
// Phase 2: SpMM, QUARTER-WAVE per row, 32-edge superblock, 256-thr blocks
// (R7's best packing). R12 fix: quarter LDS regions STAGGERED by 40 ints
// (32 used + 8 pad) -> quarter bases land on banks {0,8,16,24}:
//   * ds_read_b128 of cols: 4 quarters hit DISJOINT bank quads (was: all
//     quarters on the same 4 banks -> 4-way conflict on every cols-read,
//     1.6M times, ON the gather-address chain; R10/R11's 240K
//     SQ_LDS_BANK_CONFLICT)
//   * ds_write: exactly 2 lanes/bank (free, m136)
// Rest frozen: meta 2 edges/lane nt + scale gather (dummy c=0/vp=0);
// 32 u32x2 gathers batch-issued unconditionally; f32x2 pk_fma decode with
// 8-edge early-exit; scalar S quarter-reduce; lane-local epilogue.
// ---------------------------------------------------------------------------
#define ACCD(word, j0, vv)                                                \
  do {                                                                    \
    f32x2 lo_, hi_;                                                       \
    lo_[0] = (float)((word) & 0xFFu);                                     \
    lo_[1] = (float)(((word) >> 8) & 0xFFu);                              \
    hi_[0] = (float)(((word) >> 16) & 0xFFu);                             \
    hi_[1] = (float)((word) >> 24);                                       \
    acc2[(j0)]     = __builtin_elementwise_fma(vv, lo_, acc2[(j0)]);      \
    acc2[(j0) + 1] = __builtin_elementwise_fma(vv, hi_, acc2[(j0) + 1]);  \
  } while (0)

#define ACC8PK(U, V)                                                      \
  do {                                                                    \
    const f32x2 vv_ = {(V), (V)};                                         \
    ACCD((U)[0], 0, vv_);                                                 \
    ACCD((U)[1], 2, vv_);                                                 \
  } while (0)

__global__ __launch_bounds__(256) void spmm_qwave(
    const unsigned char* __restrict__ xwq, const float* __restrict__ scale,
    const float* __restrict__ edge_val, const int* __restrict__ edge_col,
    const int* __restrict__ row_ptr, const float* __restrict__ bias,
    float* __restrict__ out, int n) {
  __shared__ int   cbuf[16 * 40];   // 16 quarters x (32 used + 8 pad)
  __shared__ float vbuf[16 * 40];
  const int tid = threadIdx.x;
  const int row = (int)((blockIdx.x * 256 + tid) >> 4);
  if (row >= n) return;
  const int li = tid & 15;          // lane-in-quarter: owns ch li*8..li*8+7
  const int qb = (tid >> 4) * 40;   // staggered quarter base (bank 8q mod 32)
  const u32x2* __restrict__ xw2 = (const u32x2*)xwq;  // 16 u32x2 per row

  const int start = row_ptr[row], end = row_ptr[row + 1];

  f32x2 acc2[4];
#pragma unroll
  for (int j = 0; j < 4; ++j) acc2[j] = (f32x2){0.f, 0.f};
  float S = 0.f;  // per-lane sum of vp (offset correction)

  for (int e0 = start; e0 < end; e0 += 32) {
    // meta: 2 edges per lane, independent back-to-back chains
    const int ea = e0 + li, eb = e0 + 16 + li;
    int   c0 = 0, c1 = 0;
    float v0 = 0.f, v1 = 0.f;
    if (ea < end) {
      c0 = __builtin_nontemporal_load(edge_col + ea);
      v0 = __builtin_nontemporal_load(edge_val + ea) * scale[c0];
    }
    if (eb < end) {
      c1 = __builtin_nontemporal_load(edge_col + eb);
      v1 = __builtin_nontemporal_load(edge_val + eb) * scale[c1];
    }
    S += v0 + v1;
    cbuf[qb + li] = c0;  cbuf[qb + 16 + li] = c1;   // wave-private slab:
    vbuf[qb + li] = v0;  vbuf[qb + 16 + li] = v1;   // in-wave DS ordering

    // batch-issue all 32 gathers (cols read 4-at-a-time via ds_read_b128;
    // staggered bases -> conflict-free across quarters)
    u32x2 u[32];
#pragma unroll
    for (int it4 = 0; it4 < 8; ++it4) {
      const int4 c4 = *(const int4*)&cbuf[qb + it4 * 4];
      u[it4 * 4 + 0] = xw2[c4.x * 16 + li];
      u[it4 * 4 + 1] = xw2[c4.y * 16 + li];
      u[it4 * 4 + 2] = xw2[c4.z * 16 + li];
      u[it4 * 4 + 3] = xw2[c4.w * 16 + li];
    }

    // decode: early-exit at 8-edge granularity (wave-uniform break)
#pragma unroll
    for (int g = 0; g < 4; ++g) {
      if (e0 + g * 8 >= end) break;
      const f32x4 va = *(const f32x4*)&vbuf[qb + g * 8];
      const f32x4 vb = *(const f32x4*)&vbuf[qb + g * 8 + 4];
      ACC8PK(u[g * 8 + 0], va[0]);
      ACC8PK(u[g * 8 + 1], va[1]);
      ACC8PK(u[g * 8 + 2], va[2]);
      ACC8PK(u[g * 8 + 3], va[3]);
      ACC8PK(u[g * 8 + 4], vb[0]);
      ACC8PK(u[g * 8 + 5], vb[1]);
      ACC8PK(u[g * 8 + 6], vb[2]);
      ACC8PK(u[g * 8 + 7], vb[3]);
    }
  }

  // S over the quarter's 16 lanes (each owned distinct edges)
  S += __shfl_xor(S, 1);
  S += __shfl_xor(S, 2);
  S += __shfl_xor(S, 4);
  S += __shfl_xor(S, 8);

  // epilogue: lane-local 8 channels, bias+ReLU, direct store — no masking
  const float off = 128.f * S;
  const float* a = (const float*)acc2;
  const int cb = li * 8;
  const f32x4 b0 = *(const f32x4*)&bias[cb];
  const f32x4 b1 = *(const f32x4*)&bias[cb + 4];
  f32x4 o0, o1;
  o0[0] = fmaxf(a[0] - off + b0[0], 0.f);
  o0[1] = fmaxf(a[1] - off + b0[1], 0.f);
  o0[2] = fmaxf(a[2] - off + b0[2], 0.f);
  o0[3] = fmaxf(a[3] - off + b0[3], 0.f);
  o1[0] = fmaxf(a[4] - off + b1[0], 0.f);
  o1[1] = fmaxf(a[5] - off + b1[1], 0.f);
  o1[2] = fmaxf(a[6] - off + b1[2], 0.f);
  o1[3] = fmaxf(a[7] - off + b1[3], 0.f);
  __builtin_nontemporal_store(o0, (f32x4*)&out[(size_t)row * CH + cb]);
  __builtin_nontemporal_store(o1, (f32x4*)&out[(size_t)row * CH + cb + 4]);
}

extern "C" void kernel_launch(void* const* d_in, const int* in_sizes, int n_in,
                              void* d_out, int out_size, void* d_ws, size_t ws_size,
                              hipStream_t stream) {
  const float* x        = (const float*)d_in[0];
  const float* kernel   = (const float*)d_in[1];
  const float* bias     = (const float*)d_in[2];
  const float* edge_val = (const float*)d_in[3];
  const int*   edge_row = (const int*)d_in[4];
  const int*   edge_col = (const int*)d_in[5];
  float* out = (float*)d_out;

  const int n       = in_sizes[0] / F_IN;   // 100000
  const int n_edges = in_sizes[3];          // 3200000

  // ws layout: [xwq: n*CH int8 = 12.8 MB][scale: n f32][row_ptr: (n+1) int]
  unsigned char* xwq = (unsigned char*)d_ws;
  float* scale = (float*)((char*)d_ws + (size_t)n * CH);
  int* rowptr  = (int*)((char*)d_ws + (size_t)n * CH + (size_t)n * sizeof(float));

  // Phase 1 (fused): XW = X @ W (bf16 MFMA) + int8 quant + boundary-scan rowptr
  const int GB = (n + 127) / 128;
  const int RB = (n_edges / 4 + 511) / 512;
  gemm_rowptr_fused<<<GB + RB, 512, 0, stream>>>(x, kernel, xwq, scale,
                                                 edge_row, rowptr,
                                                 n, n_edges, GB);

  // Phase 2: SpMM + bias + ReLU. 16 rows per 256-thr block (quarter-wave/row).
  const int blocks = (n * 16 + 255) / 256;
  spmm_qwave<<<blocks, 256, 0, stream>>>(xwq, scale, edge_val, edge_col,
                                         rowptr, bias, out, n);
}

// Round 13
// 106.998 us; speedup vs baseline: 1.1710x; 1.0027x over previous
//
#include <hip/hip_runtime.h>

#define F_IN 128
#define CH   128

typedef __attribute__((ext_vector_type(8))) short bf16x8;
typedef __attribute__((ext_vector_type(4))) float f32x4;
typedef __attribute__((ext_vector_type(2))) float f32x2;
typedef __attribute__((ext_vector_type(2))) unsigned u32x2;

// f32 -> bf16 round-to-nearest-even
static __device__ __forceinline__ ushort f2b(float f) {
  union { float f; unsigned u; } v; v.f = f;
  const unsigned u = v.u;
  return (ushort)((u + 0x7FFFu + ((u >> 16) & 1u)) >> 16);
}

// ---------------------------------------------------------------------------
// Phase 1 (fused): blocks [0, gemm_blocks) do XW = X @ W via bf16 MFMA,
//   then quantize each output row to int8 (offset-binary, per-node scale
//   s[r] = rowmax/127) -> 12.8 MB table + 400 KB scales. 128 rows/block.
//   Quant epilogue via wave-private LDS slab -> coalesced u32x2 stores (R11).
// blocks [gemm_blocks, ...): row_ptr boundary scan, 4 edges/thread (int4).
// mfma_f32_16x16x32_bf16 layouts (guide §3, m89-verified):
//   A frag: row = lane&15, k = (lane>>4)*8 + j
//   B frag: col = lane&15, k = (lane>>4)*8 + j
//   C/D   : col = lane&15, row = (lane>>4)*4 + reg
// ---------------------------------------------------------------------------
__global__ __launch_bounds__(512) void gemm_rowptr_fused(
    const float* __restrict__ x, const float* __restrict__ w,
    unsigned char* __restrict__ xwq, float* __restrict__ scale,
    const int* __restrict__ edge_row, int* __restrict__ row_ptr,
    int n, int n_edges, int gemm_blocks) {
  __shared__ __align__(16) ushort Wt[F_IN * CH];  // W^T, swizzled, 32 KB
  const int t = threadIdx.x;

  if ((int)blockIdx.x >= gemm_blocks) {
    // ---- rowptr tail blocks: boundary scan, 4 edges per thread ----
    const int base = (((int)blockIdx.x - gemm_blocks) * 512 + t) * 4;
    if (base < n_edges) {
      const int4 er = *(const int4*)&edge_row[base];
      const int nxt = (base + 4 < n_edges) ? edge_row[base + 4] : n;
      if (base == 0) {
        for (int r = 0; r <= er.x; ++r) row_ptr[r] = 0;
      }
      for (int r = er.x + 1; r <= er.y; ++r) row_ptr[r] = base + 1;
      for (int r = er.y + 1; r <= er.z; ++r) row_ptr[r] = base + 2;
      for (int r = er.z + 1; r <= er.w; ++r) row_ptr[r] = base + 3;
      for (int r = er.w + 1; r <= nxt;  ++r) row_ptr[r] = base + 4;
    }
    return;
  }

  // ---- GEMM blocks ----
  // stage W^T as bf16 with XOR swizzle: byte ^= (col&7)<<4
  for (int i = t; i < (F_IN * CH) / 4; i += 512) {
    const int k  = i >> 5;          // 0..127
    const int n4 = (i & 31) << 2;   // 0,4,...,124
    const f32x4 wv = *(const f32x4*)&w[k * CH + n4];
#pragma unroll
    for (int q = 0; q < 4; ++q) {
      const int nn = n4 + q;
      const int byte = (nn * 256 + k * 2) ^ ((nn & 7) << 4);
      *(ushort*)((char*)Wt + byte) = f2b(wv[q]);
    }
  }
  __syncthreads();

  const int wave = t >> 6, lane = t & 63;
  const int li   = lane & 15;
  const int kgrp = (lane >> 4) * 8;
  const int R0   = blockIdx.x * 128 + wave * 16;
  const int arow = R0 + li;

  // A fragments (4 K-steps), f32->bf16 in-register; x read-once -> nt loads
  bf16x8 a[4];
#pragma unroll
  for (int s = 0; s < 4; ++s) {
    if (arow < n) {
      const f32x4 p0 = __builtin_nontemporal_load(
          (const f32x4*)&x[arow * F_IN + s * 32 + kgrp]);
      const f32x4 p1 = __builtin_nontemporal_load(
          (const f32x4*)&x[arow * F_IN + s * 32 + kgrp + 4]);
#pragma unroll
      for (int j = 0; j < 4; ++j) {
        a[s][j]     = (short)f2b(p0[j]);
        a[s][j + 4] = (short)f2b(p1[j]);
      }
    } else {
#pragma unroll
      for (int j = 0; j < 8; ++j) a[s][j] = (short)0;
    }
  }

  f32x4 acc[8];
#pragma unroll
  for (int t8 = 0; t8 < 8; ++t8) acc[t8] = (f32x4){0.f, 0.f, 0.f, 0.f};

#pragma unroll
  for (int t8 = 0; t8 < 8; ++t8) {
    const int col = t8 * 16 + li;
#pragma unroll
    for (int s = 0; s < 4; ++s) {
      const int byte = (col * 256 + (s * 32 + kgrp) * 2) ^ ((col & 7) << 4);
      const bf16x8 b = *(const bf16x8*)((const char*)Wt + byte);
      acc[t8] = __builtin_amdgcn_mfma_f32_16x16x32_bf16(a[s], b, acc[t8], 0, 0, 0);
    }
  }

  // Epilogue A: per-row absmax (shfl over 16 channel-lanes) + scale store
  float inv4[4];
  const int r0 = R0 + (lane >> 4) * 4;
#pragma unroll
  for (int i = 0; i < 4; ++i) {
    float m = 0.f;
#pragma unroll
    for (int t8 = 0; t8 < 8; ++t8) m = fmaxf(m, fabsf(acc[t8][i]));
    m = fmaxf(m, __shfl_xor(m, 1));
    m = fmaxf(m, __shfl_xor(m, 2));
    m = fmaxf(m, __shfl_xor(m, 4));
    m = fmaxf(m, __shfl_xor(m, 8));
    inv4[i] = (m > 1e-20f) ? 127.f / m : 0.f;
    const int rr = r0 + i;
    if (rr < n && li == 0) scale[rr] = m * (1.f / 127.f);
  }

  // Epilogue B: quantize through wave-private LDS slab -> coalesced stores.
  __syncthreads();  // all waves done reading Wt; safe to reuse as byte buffer
  unsigned char* qb8 = (unsigned char*)Wt + wave * 2048;  // 16 rows x 128 B
#pragma unroll
  for (int i = 0; i < 4; ++i) {
    const int rl = (lane >> 4) * 4 + i;   // row-local 0..15
#pragma unroll
    for (int t8 = 0; t8 < 8; ++t8) {
      // |acc|*inv <= 127 by construction; +128 -> [1,255], no clamp
      const float q = rintf(acc[t8][i] * inv4[i]) + 128.f;
      qb8[rl * 128 + t8 * 16 + li] = (unsigned char)q;
    }
  }
  // wave-private region: compiler orders ds reads after writes via lgkmcnt
#pragma unroll
  for (int p = 0; p < 4; ++p) {
    const int idx = p * 64 + lane;        // 0..255
    const int rl  = idx >> 4;             // row-local 0..15
    const int off = (idx & 15) * 8;       // byte offset in row
    const int rrow = blockIdx.x * 128 + wave * 16 + rl;
    if (rrow < n) {
      const u32x2 v = *(const u32x2*)&qb8[rl * 128 + off];
      *(u32x2*)&xwq[(size_t)rrow * CH + off] = v;
    }
  }
}

// ---------------------------------------------------------------------------
// Phase 2: SpMM, QUARTER-WAVE per row, 32-edge superblock, 256-thr blocks.
// R13: __launch_bounds__(256, 4) — raise the VGPR budget to 128 so the
// compiler can KEEP THE FULL 32-GATHER BATCH LIVE (R5-R12 allocated only
// 36-40 VGPRs: the u[32] batch was silently sub-batched with vmcnt waits
// between, capping per-wave outstanding lines at ~8; per-CU concurrency
// ~136 lines vs the ~400 this structure intends). Resident waves barely
// change (measured 53% ~= 17/CU; new cap 16/CU) while per-wave MLP
// quadruples. This is the discriminating test of the latency*concurrency
// model: VGPR>=90 + flat time => HW request-queue cap => roofline.
// Rest frozen from R12: meta 2 edges/lane nt + scale gather (dummy
// c=0/vp=0); staggered LDS slab; 32 u32x2 gathers batch-issued; f32x2
// pk_fma decode with 8-edge early-exit; scalar S quarter-reduce;
// lane-local epilogue (no cross-lane acc reduction).
// ---------------------------------------------------------------------------
#define ACCD(word, j0, vv)                                                \
  do {                                                                    \
    f32x2 lo_, hi_;                                                       \
    lo_[0] = (float)((word) & 0xFFu);                                     \
    lo_[1] = (float)(((word) >> 8) & 0xFFu);                              \
    hi_[0] = (float)(((word) >> 16) & 0xFFu);                             \
    hi_[1] = (float)((word) >> 24);                                       \
    acc2[(j0)]     = __builtin_elementwise_fma(vv, lo_, acc2[(j0)]);      \
    acc2[(j0) + 1] = __builtin_elementwise_fma(vv, hi_, acc2[(j0) + 1]);  \
  } while (0)

#define ACC8PK(U, V)                                                      \
  do {                                                                    \
    const f32x2 vv_ = {(V), (V)};                                         \
    ACCD((U)[0], 0, vv_);                                                 \
    ACCD((U)[1], 2, vv_);                                                 \
  } while (0)

__global__ __launch_bounds__(256, 4) void spmm_qwave(
    const unsigned char* __restrict__ xwq, const float* __restrict__ scale,
    const float* __restrict__ edge_val, const int* __restrict__ edge_col,
    const int* __restrict__ row_ptr, const float* __restrict__ bias,
    float* __restrict__ out, int n) {
  __shared__ int   cbuf[16 * 40];   // 16 quarters x (32 used + 8 pad)
  __shared__ float vbuf[16 * 40];
  const int tid = threadIdx.x;
  const int row = (int)((blockIdx.x * 256 + tid) >> 4);
  if (row >= n) return;
  const int li = tid & 15;          // lane-in-quarter: owns ch li*8..li*8+7
  const int qb = (tid >> 4) * 40;   // staggered quarter base
  const u32x2* __restrict__ xw2 = (const u32x2*)xwq;  // 16 u32x2 per row

  const int start = row_ptr[row], end = row_ptr[row + 1];

  f32x2 acc2[4];
#pragma unroll
  for (int j = 0; j < 4; ++j) acc2[j] = (f32x2){0.f, 0.f};
  float S = 0.f;  // per-lane sum of vp (offset correction)

  for (int e0 = start; e0 < end; e0 += 32) {
    // meta: 2 edges per lane, independent back-to-back chains
    const int ea = e0 + li, eb = e0 + 16 + li;
    int   c0 = 0, c1 = 0;
    float v0 = 0.f, v1 = 0.f;
    if (ea < end) {
      c0 = __builtin_nontemporal_load(edge_col + ea);
      v0 = __builtin_nontemporal_load(edge_val + ea) * scale[c0];
    }
    if (eb < end) {
      c1 = __builtin_nontemporal_load(edge_col + eb);
      v1 = __builtin_nontemporal_load(edge_val + eb) * scale[c1];
    }
    S += v0 + v1;
    cbuf[qb + li] = c0;  cbuf[qb + 16 + li] = c1;   // wave-private slab:
    vbuf[qb + li] = v0;  vbuf[qb + 16 + li] = v1;   // in-wave DS ordering

    // batch-issue all 32 gathers (cols read 4-at-a-time via ds_read_b128);
    // with the 128-VGPR budget the whole batch stays live -> 32 outstanding
    u32x2 u[32];
#pragma unroll
    for (int it4 = 0; it4 < 8; ++it4) {
      const int4 c4 = *(const int4*)&cbuf[qb + it4 * 4];
      u[it4 * 4 + 0] = xw2[c4.x * 16 + li];
      u[it4 * 4 + 1] = xw2[c4.y * 16 + li];
      u[it4 * 4 + 2] = xw2[c4.z * 16 + li];
      u[it4 * 4 + 3] = xw2[c4.w * 16 + li];
    }

    // decode: early-exit at 8-edge granularity (wave-uniform break)
#pragma unroll
    for (int g = 0; g < 4; ++g) {
      if (e0 + g * 8 >= end) break;
      const f32x4 va = *(const f32x4*)&vbuf[qb + g * 8];
      const f32x4 vb = *(const f32x4*)&vbuf[qb + g * 8 + 4];
      ACC8PK(u[g * 8 + 0], va[0]);
      ACC8PK(u[g * 8 + 1], va[1]);
      ACC8PK(u[g * 8 + 2], va[2]);
      ACC8PK(u[g * 8 + 3], va[3]);
      ACC8PK(u[g * 8 + 4], vb[0]);
      ACC8PK(u[g * 8 + 5], vb[1]);
      ACC8PK(u[g * 8 + 6], vb[2]);
      ACC8PK(u[g * 8 + 7], vb[3]);
    }
  }

  // S over the quarter's 16 lanes (each owned distinct edges)
  S += __shfl_xor(S, 1);
  S += __shfl_xor(S, 2);
  S += __shfl_xor(S, 4);
  S += __shfl_xor(S, 8);

  // epilogue: lane-local 8 channels, bias+ReLU, direct store — no masking
  const float off = 128.f * S;
  const float* a = (const float*)acc2;
  const int cb = li * 8;
  const f32x4 b0 = *(const f32x4*)&bias[cb];
  const f32x4 b1 = *(const f32x4*)&bias[cb + 4];
  f32x4 o0, o1;
  o0[0] = fmaxf(a[0] - off + b0[0], 0.f);
  o0[1] = fmaxf(a[1] - off + b0[1], 0.f);
  o0[2] = fmaxf(a[2] - off + b0[2], 0.f);
  o0[3] = fmaxf(a[3] - off + b0[3], 0.f);
  o1[0] = fmaxf(a[4] - off + b1[0], 0.f);
  o1[1] = fmaxf(a[5] - off + b1[1], 0.f);
  o1[2] = fmaxf(a[6] - off + b1[2], 0.f);
  o1[3] = fmaxf(a[7] - off + b1[3], 0.f);
  __builtin_nontemporal_store(o0, (f32x4*)&out[(size_t)row * CH + cb]);
  __builtin_nontemporal_store(o1, (f32x4*)&out[(size_t)row * CH + cb + 4]);
}

extern "C" void kernel_launch(void* const* d_in, const int* in_sizes, int n_in,
                              void* d_out, int out_size, void* d_ws, size_t ws_size,
                              hipStream_t stream) {
  const float* x        = (const float*)d_in[0];
  const float* kernel   = (const float*)d_in[1];
  const float* bias     = (const float*)d_in[2];
  const float* edge_val = (const float*)d_in[3];
  const int*   edge_row = (const int*)d_in[4];
  const int*   edge_col = (const int*)d_in[5];
  float* out = (float*)d_out;

  const int n       = in_sizes[0] / F_IN;   // 100000
  const int n_edges = in_sizes[3];          // 3200000

  // ws layout: [xwq: n*CH int8 = 12.8 MB][scale: n f32][row_ptr: (n+1) int]
  unsigned char* xwq = (unsigned char*)d_ws;
  float* scale = (float*)((char*)d_ws + (size_t)n * CH);
  int* rowptr  = (int*)((char*)d_ws + (size_t)n * CH + (size_t)n * sizeof(float));

  // Phase 1 (fused): XW = X @ W (bf16 MFMA) + int8 quant + boundary-scan rowptr
  const int GB = (n + 127) / 128;
  const int RB = (n_edges / 4 + 511) / 512;
  gemm_rowptr_fused<<<GB + RB, 512, 0, stream>>>(x, kernel, xwq, scale,
                                                 edge_row, rowptr,
                                                 n, n_edges, GB);

  // Phase 2: SpMM + bias + ReLU. 16 rows per 256-thr block (quarter-wave/row).
  const int blocks = (n * 16 + 255) / 256;
  spmm_qwave<<<blocks, 256, 0, stream>>>(xwq, scale, edge_val, edge_col,
                                         rowptr, bias, out, n);
}

// Round 14
// 106.613 us; speedup vs baseline: 1.1752x; 1.0036x over previous
//
#include <hip/hip_runtime.h>

#define F_IN 128
#define CH   128

typedef __attribute__((ext_vector_type(8))) short bf16x8;
typedef __attribute__((ext_vector_type(4))) float f32x4;
typedef __attribute__((ext_vector_type(2))) float f32x2;
typedef __attribute__((ext_vector_type(2))) unsigned u32x2;

// f32 -> bf16 round-to-nearest-even
static __device__ __forceinline__ ushort f2b(float f) {
  union { float f; unsigned u; } v; v.f = f;
  const unsigned u = v.u;
  return (ushort)((u + 0x7FFFu + ((u >> 16) & 1u)) >> 16);
}

// ---------------------------------------------------------------------------
// Phase 1 (fused): blocks [0, gemm_blocks) do XW = X @ W via bf16 MFMA,
//   then quantize each output row to int8 (offset-binary, per-node scale
//   s[r] = rowmax/127) -> 12.8 MB table + 400 KB scales. 128 rows/block.
//   Quant epilogue via wave-private LDS slab -> coalesced u32x2 stores (R11).
// blocks [gemm_blocks, ...): row_ptr boundary scan, 4 edges/thread (int4).
// mfma_f32_16x16x32_bf16 layouts (guide §3, m89-verified):
//   A frag: row = lane&15, k = (lane>>4)*8 + j
//   B frag: col = lane&15, k = (lane>>4)*8 + j
//   C/D   : col = lane&15, row = (lane>>4)*4 + reg
// ---------------------------------------------------------------------------
__global__ __launch_bounds__(512) void gemm_rowptr_fused(
    const float* __restrict__ x, const float* __restrict__ w,
    unsigned char* __restrict__ xwq, float* __restrict__ scale,
    const int* __restrict__ edge_row, int* __restrict__ row_ptr,
    int n, int n_edges, int gemm_blocks) {
  __shared__ __align__(16) ushort Wt[F_IN * CH];  // W^T, swizzled, 32 KB
  const int t = threadIdx.x;

  if ((int)blockIdx.x >= gemm_blocks) {
    // ---- rowptr tail blocks: boundary scan, 4 edges per thread ----
    const int base = (((int)blockIdx.x - gemm_blocks) * 512 + t) * 4;
    if (base < n_edges) {
      const int4 er = *(const int4*)&edge_row[base];
      const int nxt = (base + 4 < n_edges) ? edge_row[base + 4] : n;
      if (base == 0) {
        for (int r = 0; r <= er.x; ++r) row_ptr[r] = 0;
      }
      for (int r = er.x + 1; r <= er.y; ++r) row_ptr[r] = base + 1;
      for (int r = er.y + 1; r <= er.z; ++r) row_ptr[r] = base + 2;
      for (int r = er.z + 1; r <= er.w; ++r) row_ptr[r] = base + 3;
      for (int r = er.w + 1; r <= nxt;  ++r) row_ptr[r] = base + 4;
    }
    return;
  }

  // ---- GEMM blocks ----
  // stage W^T as bf16 with XOR swizzle: byte ^= (col&7)<<4
  for (int i = t; i < (F_IN * CH) / 4; i += 512) {
    const int k  = i >> 5;          // 0..127
    const int n4 = (i & 31) << 2;   // 0,4,...,124
    const f32x4 wv = *(const f32x4*)&w[k * CH + n4];
#pragma unroll
    for (int q = 0; q < 4; ++q) {
      const int nn = n4 + q;
      const int byte = (nn * 256 + k * 2) ^ ((nn & 7) << 4);
      *(ushort*)((char*)Wt + byte) = f2b(wv[q]);
    }
  }
  __syncthreads();

  const int wave = t >> 6, lane = t & 63;
  const int li   = lane & 15;
  const int kgrp = (lane >> 4) * 8;
  const int R0   = blockIdx.x * 128 + wave * 16;
  const int arow = R0 + li;

  // A fragments (4 K-steps), f32->bf16 in-register; x read-once -> nt loads
  bf16x8 a[4];
#pragma unroll
  for (int s = 0; s < 4; ++s) {
    if (arow < n) {
      const f32x4 p0 = __builtin_nontemporal_load(
          (const f32x4*)&x[arow * F_IN + s * 32 + kgrp]);
      const f32x4 p1 = __builtin_nontemporal_load(
          (const f32x4*)&x[arow * F_IN + s * 32 + kgrp + 4]);
#pragma unroll
      for (int j = 0; j < 4; ++j) {
        a[s][j]     = (short)f2b(p0[j]);
        a[s][j + 4] = (short)f2b(p1[j]);
      }
    } else {
#pragma unroll
      for (int j = 0; j < 8; ++j) a[s][j] = (short)0;
    }
  }

  f32x4 acc[8];
#pragma unroll
  for (int t8 = 0; t8 < 8; ++t8) acc[t8] = (f32x4){0.f, 0.f, 0.f, 0.f};

#pragma unroll
  for (int t8 = 0; t8 < 8; ++t8) {
    const int col = t8 * 16 + li;
#pragma unroll
    for (int s = 0; s < 4; ++s) {
      const int byte = (col * 256 + (s * 32 + kgrp) * 2) ^ ((col & 7) << 4);
      const bf16x8 b = *(const bf16x8*)((const char*)Wt + byte);
      acc[t8] = __builtin_amdgcn_mfma_f32_16x16x32_bf16(a[s], b, acc[t8], 0, 0, 0);
    }
  }

  // Epilogue A: per-row absmax (shfl over 16 channel-lanes) + scale store
  float inv4[4];
  const int r0 = R0 + (lane >> 4) * 4;
#pragma unroll
  for (int i = 0; i < 4; ++i) {
    float m = 0.f;
#pragma unroll
    for (int t8 = 0; t8 < 8; ++t8) m = fmaxf(m, fabsf(acc[t8][i]));
    m = fmaxf(m, __shfl_xor(m, 1));
    m = fmaxf(m, __shfl_xor(m, 2));
    m = fmaxf(m, __shfl_xor(m, 4));
    m = fmaxf(m, __shfl_xor(m, 8));
    inv4[i] = (m > 1e-20f) ? 127.f / m : 0.f;
    const int rr = r0 + i;
    if (rr < n && li == 0) scale[rr] = m * (1.f / 127.f);
  }

  // Epilogue B: quantize through wave-private LDS slab -> coalesced stores.
  __syncthreads();  // all waves done reading Wt; safe to reuse as byte buffer
  unsigned char* qb8 = (unsigned char*)Wt + wave * 2048;  // 16 rows x 128 B
#pragma unroll
  for (int i = 0; i < 4; ++i) {
    const int rl = (lane >> 4) * 4 + i;   // row-local 0..15
#pragma unroll
    for (int t8 = 0; t8 < 8; ++t8) {
      // |acc|*inv <= 127 by construction; +128 -> [1,255], no clamp
      const float q = rintf(acc[t8][i] * inv4[i]) + 128.f;
      qb8[rl * 128 + t8 * 16 + li] = (unsigned char)q;
    }
  }
  // wave-private region: compiler orders ds reads after writes via lgkmcnt
#pragma unroll
  for (int p = 0; p < 4; ++p) {
    const int idx = p * 64 + lane;        // 0..255
    const int rl  = idx >> 4;             // row-local 0..15
    const int off = (idx & 15) * 8;       // byte offset in row
    const int rrow = blockIdx.x * 128 + wave * 16 + rl;
    if (rrow < n) {
      const u32x2 v = *(const u32x2*)&qb8[rl * 128 + off];
      *(u32x2*)&xwq[(size_t)rrow * CH + off] = v;
    }
  }
}

// ---------------------------------------------------------------------------
// Phase 2: SpMM, QUARTER-WAVE per row, 32-edge superblock, 256-thr blocks.
// R14: sched_barrier(0) between the gather batch and decode — R13 showed
// __launch_bounds__ alone doesn't change codegen (VGPR stayed 40: compiler
// sub-batched the 32 gathers at ~8 live, capping per-wave outstanding lines).
// The barrier pins ALL 32 gathers before ANY decode -> allocator must hold
// the full batch (VGPR ~100+, verify in counters) -> per-wave MLP 8 -> 32.
// This is the actual execution of R13's concurrency experiment.
// Pre-committed falsifier: VGPR>=100 and time flat => per-CU request-queue
// cap => roofline next round.
// Rest frozen from R12/R13: quarter-wave (lane li owns ch li*8..li*8+7,
// no cross-lane acc reduction); meta 2 edges/lane nt + scale gather (dummy
// c=0/vp=0); staggered LDS slab; f32x2 pk_fma decode with 8-edge
// early-exit; scalar S quarter-reduce; lane-local epilogue.
// ---------------------------------------------------------------------------
#define ACCD(word, j0, vv)                                                \
  do {                                                                    \
    f32x2 lo_, hi_;                                                       \
    lo_[0] = (float)((word) & 0xFFu);                                     \
    lo_[1] = (float)(((word) >> 8) & 0xFFu);                              \
    hi_[0] = (float)(((word) >> 16) & 0xFFu);                             \
    hi_[1] = (float)((word) >> 24);                                       \
    acc2[(j0)]     = __builtin_elementwise_fma(vv, lo_, acc2[(j0)]);      \
    acc2[(j0) + 1] = __builtin_elementwise_fma(vv, hi_, acc2[(j0) + 1]);  \
  } while (0)

#define ACC8PK(U, V)                                                      \
  do {                                                                    \
    const f32x2 vv_ = {(V), (V)};                                         \
    ACCD((U)[0], 0, vv_);                                                 \
    ACCD((U)[1], 2, vv_);                                                 \
  } while (0)

__global__ __launch_bounds__(256, 4) void spmm_qwave(
    const unsigned char* __restrict__ xwq, const float* __restrict__ scale,
    const float* __restrict__ edge_val, const int* __restrict__ edge_col,
    const int* __restrict__ row_ptr, const float* __restrict__ bias,
    float* __restrict__ out, int n) {
  __shared__ int   cbuf[16 * 40];   // 16 quarters x (32 used + 8 pad)
  __shared__ float vbuf[16 * 40];
  const int tid = threadIdx.x;
  const int row = (int)((blockIdx.x * 256 + tid) >> 4);
  if (row >= n) return;
  const int li = tid & 15;          // lane-in-quarter: owns ch li*8..li*8+7
  const int qb = (tid >> 4) * 40;   // staggered quarter base
  const u32x2* __restrict__ xw2 = (const u32x2*)xwq;  // 16 u32x2 per row

  const int start = row_ptr[row], end = row_ptr[row + 1];

  f32x2 acc2[4];
#pragma unroll
  for (int j = 0; j < 4; ++j) acc2[j] = (f32x2){0.f, 0.f};
  float S = 0.f;  // per-lane sum of vp (offset correction)

  for (int e0 = start; e0 < end; e0 += 32) {
    // meta: 2 edges per lane, independent back-to-back chains
    const int ea = e0 + li, eb = e0 + 16 + li;
    int   c0 = 0, c1 = 0;
    float v0 = 0.f, v1 = 0.f;
    if (ea < end) {
      c0 = __builtin_nontemporal_load(edge_col + ea);
      v0 = __builtin_nontemporal_load(edge_val + ea) * scale[c0];
    }
    if (eb < end) {
      c1 = __builtin_nontemporal_load(edge_col + eb);
      v1 = __builtin_nontemporal_load(edge_val + eb) * scale[c1];
    }
    S += v0 + v1;
    cbuf[qb + li] = c0;  cbuf[qb + 16 + li] = c1;   // wave-private slab:
    vbuf[qb + li] = v0;  vbuf[qb + 16 + li] = v1;   // in-wave DS ordering

    // batch-issue all 32 gathers (cols read 4-at-a-time via ds_read_b128)
    u32x2 u[32];
#pragma unroll
    for (int it4 = 0; it4 < 8; ++it4) {
      const int4 c4 = *(const int4*)&cbuf[qb + it4 * 4];
      u[it4 * 4 + 0] = xw2[c4.x * 16 + li];
      u[it4 * 4 + 1] = xw2[c4.y * 16 + li];
      u[it4 * 4 + 2] = xw2[c4.z * 16 + li];
      u[it4 * 4 + 3] = xw2[c4.w * 16 + li];
    }

    // Pin the schedule: no gather may sink past this point -> all 32 issue
    // before the first decode wait; the whole batch stays register-live.
    __builtin_amdgcn_sched_barrier(0);

    // decode: early-exit at 8-edge granularity (wave-uniform break)
#pragma unroll
    for (int g = 0; g < 4; ++g) {
      if (e0 + g * 8 >= end) break;
      const f32x4 va = *(const f32x4*)&vbuf[qb + g * 8];
      const f32x4 vb = *(const f32x4*)&vbuf[qb + g * 8 + 4];
      ACC8PK(u[g * 8 + 0], va[0]);
      ACC8PK(u[g * 8 + 1], va[1]);
      ACC8PK(u[g * 8 + 2], va[2]);
      ACC8PK(u[g * 8 + 3], va[3]);
      ACC8PK(u[g * 8 + 4], vb[0]);
      ACC8PK(u[g * 8 + 5], vb[1]);
      ACC8PK(u[g * 8 + 6], vb[2]);
      ACC8PK(u[g * 8 + 7], vb[3]);
    }
  }

  // S over the quarter's 16 lanes (each owned distinct edges)
  S += __shfl_xor(S, 1);
  S += __shfl_xor(S, 2);
  S += __shfl_xor(S, 4);
  S += __shfl_xor(S, 8);

  // epilogue: lane-local 8 channels, bias+ReLU, direct store — no masking
  const float off = 128.f * S;
  const float* a = (const float*)acc2;
  const int cb = li * 8;
  const f32x4 b0 = *(const f32x4*)&bias[cb];
  const f32x4 b1 = *(const f32x4*)&bias[cb + 4];
  f32x4 o0, o1;
  o0[0] = fmaxf(a[0] - off + b0[0], 0.f);
  o0[1] = fmaxf(a[1] - off + b0[1], 0.f);
  o0[2] = fmaxf(a[2] - off + b0[2], 0.f);
  o0[3] = fmaxf(a[3] - off + b0[3], 0.f);
  o1[0] = fmaxf(a[4] - off + b1[0], 0.f);
  o1[1] = fmaxf(a[5] - off + b1[1], 0.f);
  o1[2] = fmaxf(a[6] - off + b1[2], 0.f);
  o1[3] = fmaxf(a[7] - off + b1[3], 0.f);
  __builtin_nontemporal_store(o0, (f32x4*)&out[(size_t)row * CH + cb]);
  __builtin_nontemporal_store(o1, (f32x4*)&out[(size_t)row * CH + cb + 4]);
}

extern "C" void kernel_launch(void* const* d_in, const int* in_sizes, int n_in,
                              void* d_out, int out_size, void* d_ws, size_t ws_size,
                              hipStream_t stream) {
  const float* x        = (const float*)d_in[0];
  const float* kernel   = (const float*)d_in[1];
  const float* bias     = (const float*)d_in[2];
  const float* edge_val = (const float*)d_in[3];
  const int*   edge_row = (const int*)d_in[4];
  const int*   edge_col = (const int*)d_in[5];
  float* out = (float*)d_out;

  const int n       = in_sizes[0] / F_IN;   // 100000
  const int n_edges = in_sizes[3];          // 3200000

  // ws layout: [xwq: n*CH int8 = 12.8 MB][scale: n f32][row_ptr: (n+1) int]
  unsigned char* xwq = (unsigned char*)d_ws;
  float* scale = (float*)((char*)d_ws + (size_t)n * CH);
  int* rowptr  = (int*)((char*)d_ws + (size_t)n * CH + (size_t)n * sizeof(float));

  // Phase 1 (fused): XW = X @ W (bf16 MFMA) + int8 quant + boundary-scan rowptr
  const int GB = (n + 127) / 128;
  const int RB = (n_edges / 4 + 511) / 512;
  gemm_rowptr_fused<<<GB + RB, 512, 0, stream>>>(x, kernel, xwq, scale,
                                                 edge_row, rowptr,
                                                 n, n_edges, GB);

  // Phase 2: SpMM + bias + ReLU. 16 rows per 256-thr block (quarter-wave/row).
  const int blocks = (n * 16 + 255) / 256;
  spmm_qwave<<<blocks, 256, 0, stream>>>(xwq, scale, edge_val, edge_col,
                                         rowptr, bias, out, n);
}